// Round 1
// baseline (223.313 us; speedup 1.0000x reference)
//
#include <hip/hip_runtime.h>
#include <math.h>

#define NN 320
#define DD 256

__device__ __constant__ int c_TABLE[7][7] = {
    {0, 2, 2, 1, 1, 0, 1},
    {0, 2, 2, 2, 2, 2, 2},
    {0, 2, 2, 2, 1, 0, 2},
    {0, 2, 2, 2, 2, 2, 2},
    {0, 2, 2, 2, 1, 2, 2},
    {0, 2, 2, 2, 2, 0, 2},
    {0, 2, 2, 1, 1, 0, 1}
};

// Kernel A: one block per row i; thread j computes d2(i,j), stores
// L[i][j] = -sqrt(d2)/TEMP and E[i][j] = exp(L). Block 0 zeroes accumulators.
__global__ __launch_bounds__(NN) void pairwise_kernel(const float* __restrict__ F,
                                                      float* __restrict__ E,
                                                      float* __restrict__ L,
                                                      float* __restrict__ acc) {
    __shared__ float fi[DD];
    const int i = blockIdx.x;
    const int tid = threadIdx.x;
    if (tid < DD) fi[tid] = F[i * DD + tid];
    if (blockIdx.x == 0 && tid < 2) acc[tid] = 0.0f;
    __syncthreads();

    const int j = tid;  // blockDim == NN
    const float* __restrict__ fj = F + j * DD;
    float d2 = 0.0f;
#pragma unroll 8
    for (int d = 0; d < DD; ++d) {
        float diff = fi[d] - fj[d];
        d2 = fmaf(diff, diff, d2);
    }
    float nrm = (d2 > 0.0f) ? sqrtf(d2) : 0.0f;
    float lg = -0.5f * nrm;  // -norm / TEMP, TEMP = 2.0
    L[i * NN + j] = lg;
    E[i * NN + j] = expf(lg);
}

// Kernel B: one block per anchor k; thread i handles row i.
__global__ __launch_bounds__(NN) void anchor_kernel(const float* __restrict__ E,
                                                    const float* __restrict__ L,
                                                    const float* __restrict__ yt,
                                                    const int* __restrict__ ye,
                                                    float* __restrict__ acc) {
    __shared__ float s_pld[NN];
    __shared__ int   s_ev[NN];
    __shared__ float s_loss[NN];
    __shared__ int   s_np[NN];

    const int k = blockIdx.x;
    const int tid = threadIdx.x;
    const float tk = yt[k];
    s_pld[tid] = yt[tid] - tk;
    s_ev[tid]  = ye[tid];
    __syncthreads();

    float local_loss = 0.0f;
    int   local_np = 0;
    const int i = tid;
    if (i != k) {
        const float pldi = s_pld[i];
        const float absi = fabsf(pldi);
        const int sgn = (pldi > 0.0f) ? 1 : ((pldi < 0.0f) ? -1 : 0);
        const int cid = (s_ev[i] + 10 * s_ev[k]) * sgn;
        // searchsorted(CASE_VALS, cid): cid is always exactly one of CASE_VALS
        const int cidx = (cid == -11) ? 0 : (cid == -10) ? 1 : (cid == -1) ? 2
                       : (cid == 0)   ? 3 : (cid == 1)   ? 4 : (cid == 10) ? 5 : 6;
        float w[7];
#pragma unroll
        for (int v = 0; v < 7; ++v) {
            int m = c_TABLE[cidx][v];
            w[v] = (m == 1) ? 1.0f : (m == 2) ? 0.5f : 0.0f;
        }
        const float* __restrict__ Erow = E + i * NN;
        float denom = 0.0f;
        bool any = false;
        for (int j = 0; j < NN; ++j) {
            if (j == k || j == i) continue;
            const float pldj = s_pld[j];
            // td: 3 if pld[j] > |pld[i]|, 1 if -pld[j] > |pld[i]|, 2 if pld[j]!=0, else 0
            int td;
            if (pldj > absi)        td = 3;
            else if (-pldj > absi)  td = 1;
            else if (pldj != 0.0f)  td = 2;
            else                    td = 0;
            if (td != 0) {
                // neg = ev[j]*10+td; vidx = neg>3 ? neg-7 : neg  ==  td + 3*ev[j]
                const int vidx = td + (s_ev[j] ? 3 : 0);
                const float c = w[vidx];
                if (c > 0.0f) {
                    denom = fmaf(c, Erow[j], denom);
                    any = true;
                }
            }
        }
        if (any) {
            local_np = 1;
            local_loss = L[i * NN + k] - logf(denom);
        }
    }
    s_loss[tid] = local_loss;
    s_np[tid]   = local_np;
    __syncthreads();

    if (tid < 64) {
        float s = 0.0f;
        int   n = 0;
        for (int t = tid; t < NN; t += 64) {
            s += s_loss[t];
            n += s_np[t];
        }
#pragma unroll
        for (int off = 32; off > 0; off >>= 1) {
            s += __shfl_down(s, off);
            n += __shfl_down(n, off);
        }
        if (tid == 0 && n > 0) {
            atomicAdd(&acc[0], -s / (float)n);  // loss_k = -sum(logp)/Np, Np>0
            atomicAdd(&acc[1], 1.0f);
        }
    }
}

__global__ void finalize_kernel(const float* __restrict__ acc, float* __restrict__ out) {
    out[0] = acc[0] / acc[1];
}

extern "C" void kernel_launch(void* const* d_in, const int* in_sizes, int n_in,
                              void* d_out, int out_size, void* d_ws, size_t ws_size,
                              hipStream_t stream) {
    const float* F  = (const float*)d_in[0];   // features (320, 256) f32
    const float* yt = (const float*)d_in[1];   // y_times (320,) f32
    const int*   ye = (const int*)d_in[2];     // y_events (320,) i32
    float* out = (float*)d_out;
    float* ws  = (float*)d_ws;

    float* E   = ws;                 // NN*NN
    float* L   = ws + NN * NN;       // NN*NN
    float* acc = ws + 2 * NN * NN;   // [loss_sum, count]

    pairwise_kernel<<<NN, NN, 0, stream>>>(F, E, L, acc);
    anchor_kernel<<<NN, NN, 0, stream>>>(E, L, yt, ye, acc);
    finalize_kernel<<<1, 1, 0, stream>>>(acc, out);
}

// Round 2
// 199.521 us; speedup vs baseline: 1.1192x; 1.1192x over previous
//
#include <hip/hip_runtime.h>
#include <math.h>

#define NN 320
#define DD 256

// Packed weight rows: for cidx, bit-pack code(TABLE[cidx][v]) at 2*v, where
// code: mapped==1 -> 2, mapped==2 -> 1, mapped==0 -> 0. weight = code * 0.5.
// TABLE rows:
// 0:[0,2,2,1,1,0,1]->0x2294  1:[0,2,2,2,2,2,2]->0x1554  2:[0,2,2,2,1,0,2]->0x1254
// 3:=row1 0x1554             4:[0,2,2,2,1,2,2]->0x1654  5:[0,2,2,2,2,0,2]->0x1154
// 6:=row0 0x2294
__device__ __constant__ unsigned int c_PACK[7] =
    {0x2294u, 0x1554u, 0x1254u, 0x1554u, 0x1654u, 0x1154u, 0x2294u};

// Kernel T: LDS-tiled transpose F(320x256) -> FT(256x320); block(0,0) zeroes
// per-anchor accumulators asum[320], anp[320].
__global__ __launch_bounds__(256) void transpose_zero_kernel(
    const float* __restrict__ F, float* __restrict__ FT,
    float* __restrict__ accv /* asum[320] ++ anp[320] */) {
    __shared__ float tile[64][65];
    const int I = blockIdx.x;  // i-tile (0..4)
    const int J = blockIdx.y;  // d-tile (0..3)
    const int lane = threadIdx.x & 63;
    const int quad = threadIdx.x >> 6;  // 0..3

    if (I == 0 && J == 0) {
        for (int t = threadIdx.x; t < 2 * NN; t += 256) accv[t] = 0.0f;
    }

#pragma unroll
    for (int r0 = 0; r0 < 64; r0 += 4) {
        const int r = r0 + quad;            // local i
        tile[r][lane] = F[(I * 64 + r) * DD + J * 64 + lane];  // coalesced in d
    }
    __syncthreads();
#pragma unroll
    for (int r0 = 0; r0 < 64; r0 += 4) {
        const int d = r0 + quad;            // local d
        FT[(J * 64 + d) * NN + I * 64 + lane] = tile[lane][d]; // coalesced in i
    }
}

// Kernel A: block = row i (320 thr); lane j reads FT coalesced.
__global__ __launch_bounds__(NN) void pairwise_kernel(
    const float* __restrict__ F, const float* __restrict__ FT,
    float* __restrict__ E, float* __restrict__ L) {
    __shared__ float fi[DD];
    const int i = blockIdx.x;
    const int tid = threadIdx.x;
    if (tid < DD) fi[tid] = F[i * DD + tid];
    __syncthreads();

    const int j = tid;
    float d2 = 0.0f;
#pragma unroll 8
    for (int d = 0; d < DD; ++d) {
        float diff = fi[d] - FT[d * NN + j];
        d2 = fmaf(diff, diff, d2);
    }
    float nrm = (d2 > 0.0f) ? sqrtf(d2) : 0.0f;
    float lg = -0.5f * nrm;  // -norm/TEMP, TEMP=2
    L[i * NN + j] = lg;
    E[i * NN + j] = expf(lg);
}

// Kernel B: one wave per (anchor k, row i). blockIdx.x = k, blockIdx.y = row
// group (8 rows/block). Lanes sweep j coalesced.
__global__ __launch_bounds__(512) void anchor_kernel(
    const float* __restrict__ E, const float* __restrict__ L,
    const float* __restrict__ yt, const int* __restrict__ ye,
    float* __restrict__ accv) {
    __shared__ float s_pld[NN];
    __shared__ int   s_ev[NN];

    const int k    = blockIdx.x;
    const int tid  = threadIdx.x;
    const int wave = tid >> 6;
    const int lane = tid & 63;
    const float tk = yt[k];
    if (tid < NN) {
        s_pld[tid] = yt[tid] - tk;
        s_ev[tid]  = ye[tid];
    }
    __syncthreads();

    const int i = blockIdx.y * 8 + wave;
    if (i == k) return;  // row i==k excluded entirely (keep mask)

    const float pldi = s_pld[i];
    const float absi = fabsf(pldi);
    const int   sgn  = (pldi > 0.0f) ? 1 : ((pldi < 0.0f) ? -1 : 0);
    const int   cid  = (s_ev[i] + 10 * s_ev[k]) * sgn;
    const int   cidx = (cid == -11) ? 0 : (cid == -10) ? 1 : (cid == -1) ? 2
                     : (cid == 0)   ? 3 : (cid == 1)   ? 4 : (cid == 10) ? 5 : 6;
    const unsigned int pack = c_PACK[cidx];

    const float* __restrict__ Erow = E + i * NN;
    float acc = 0.0f;
#pragma unroll
    for (int c = 0; c < 5; ++c) {
        const int j = c * 64 + lane;
        const float pldj = s_pld[j];
        const int   evj  = s_ev[j];
        int base = (pldj > absi) ? 3 : ((-pldj > absi) ? 1
                 : ((pldj != 0.0f) ? 2 : 0));
        int vidx = base ? (base + (evj ? 3 : 0)) : 0;
        if (j == i || j == k) vidx = 0;
        const int code = (pack >> (vidx * 2)) & 3;   // weight = code * 0.5
        acc = fmaf((float)code, Erow[j], acc);
    }
#pragma unroll
    for (int off = 32; off > 0; off >>= 1) acc += __shfl_down(acc, off);

    if (lane == 0 && acc > 0.0f) {
        const float logp = L[i * NN + k] - logf(0.5f * acc);
        atomicAdd(&accv[k], logp);         // asum[k]
        atomicAdd(&accv[NN + k], 1.0f);    // anp[k]
    }
}

// Kernel C: per-anchor loss, reduce to scalar.
__global__ __launch_bounds__(NN) void finalize_kernel(
    const float* __restrict__ accv, float* __restrict__ out) {
    __shared__ float s_l[5];
    __shared__ float s_h[5];
    const int k = threadIdx.x;
    const int wave = k >> 6, lane = k & 63;
    const float np = accv[NN + k];
    float loss = (np > 0.0f) ? (-accv[k] / np) : 0.0f;
    float has  = (np > 0.0f) ? 1.0f : 0.0f;
#pragma unroll
    for (int off = 32; off > 0; off >>= 1) {
        loss += __shfl_down(loss, off);
        has  += __shfl_down(has, off);
    }
    if (lane == 0) { s_l[wave] = loss; s_h[wave] = has; }
    __syncthreads();
    if (k == 0) {
        float tl = 0.0f, th = 0.0f;
#pragma unroll
        for (int w = 0; w < 5; ++w) { tl += s_l[w]; th += s_h[w]; }
        out[0] = tl / th;
    }
}

extern "C" void kernel_launch(void* const* d_in, const int* in_sizes, int n_in,
                              void* d_out, int out_size, void* d_ws, size_t ws_size,
                              hipStream_t stream) {
    const float* F  = (const float*)d_in[0];   // features (320,256) f32
    const float* yt = (const float*)d_in[1];   // y_times (320,) f32
    const int*   ye = (const int*)d_in[2];     // y_events (320,) i32
    float* out = (float*)d_out;
    float* ws  = (float*)d_ws;

    float* FT   = ws;                          // 256*320
    float* E    = FT + DD * NN;                // 320*320
    float* L    = E + NN * NN;                 // 320*320
    float* accv = L + NN * NN;                 // asum[320] ++ anp[320]

    transpose_zero_kernel<<<dim3(5, 4), 256, 0, stream>>>(F, FT, accv);
    pairwise_kernel<<<NN, NN, 0, stream>>>(F, FT, E, L);
    anchor_kernel<<<dim3(NN, 40), 512, 0, stream>>>(E, L, yt, ye, accv);
    finalize_kernel<<<1, NN, 0, stream>>>(accv, out);
}

// Round 3
// 94.744 us; speedup vs baseline: 2.3570x; 2.1059x over previous
//
#include <hip/hip_runtime.h>
#include <math.h>

#define NN 320
#define DD 256
#define SPLIT 4                        // blocks per anchor k
#define ROWS_PER_SPLIT (NN / SPLIT)    // 80
#define WAVES 8                        // waves per 512-thr block

// Packed weight rows: code(TABLE[cidx][v]) at bit 2*v, code: mapped 1->2,
// 2->1, 0->0; weight = code*0.5. Column 0 is 0 in every row, so vidx==0
// (pld[j]==0, incl. j==k) yields weight 0 with no special-casing.
__device__ __constant__ unsigned int c_PACK[7] =
    {0x2294u, 0x1554u, 0x1254u, 0x1554u, 0x1654u, 0x1154u, 0x2294u};

// Transpose F(320x256) -> FT(256x320), LDS-tiled, conflict-free.
__global__ __launch_bounds__(256) void transpose_kernel(
    const float* __restrict__ F, float* __restrict__ FT) {
    __shared__ float tile[64][65];
    const int I = blockIdx.x;            // i-tile 0..4
    const int J = blockIdx.y;            // d-tile 0..3
    const int lane = threadIdx.x & 63;
    const int quad = threadIdx.x >> 6;   // 0..3
#pragma unroll
    for (int r0 = 0; r0 < 64; r0 += 4) {
        const int r = r0 + quad;
        tile[r][lane] = F[(I * 64 + r) * DD + J * 64 + lane];
    }
    __syncthreads();
#pragma unroll
    for (int r0 = 0; r0 < 64; r0 += 4) {
        const int d = r0 + quad;
        FT[(J * 64 + d) * NN + I * 64 + lane] = tile[lane][d];
    }
}

// One block per row i; lane j sweeps FT coalesced. Writes E only
// (L is recovered as logf(E) where needed; row/col symmetric).
__global__ __launch_bounds__(NN) void pairwise_kernel(
    const float* __restrict__ F, const float* __restrict__ FT,
    float* __restrict__ E) {
    __shared__ float fi[DD];
    const int i = blockIdx.x;
    const int tid = threadIdx.x;
    if (tid < DD) fi[tid] = F[i * DD + tid];
    __syncthreads();

    float d2 = 0.0f;
#pragma unroll 8
    for (int d = 0; d < DD; ++d) {
        float diff = fi[d] - FT[d * NN + tid];
        d2 = fmaf(diff, diff, d2);
    }
    float nrm = (d2 > 0.0f) ? sqrtf(d2) : 0.0f;
    E[i * NN + tid] = expf(-0.5f * nrm);   // exp(-norm/TEMP), TEMP=2
}

// Block (k, split): 8 waves x 10 rows each; lanes sweep j coalesced.
// No atomics: partial (sum, np) written to accv[split*NN+k] / [+4*NN].
__global__ __launch_bounds__(512) void anchor_kernel(
    const float* __restrict__ E, const float* __restrict__ yt,
    const int* __restrict__ ye, float* __restrict__ accv) {
    __shared__ float2 s_pe[NN];   // {pld_j, ev_j bit-cast}
    __shared__ float  s_Ek[NN];   // E row k (== column k by symmetry)
    __shared__ float  s_sum[WAVES];
    __shared__ float  s_np[WAVES];

    const int k     = blockIdx.x;
    const int split = blockIdx.y;
    const int tid   = threadIdx.x;
    const int wave  = tid >> 6;
    const int lane  = tid & 63;

    const float tk = yt[k];
    if (tid < NN) {
        s_pe[tid] = make_float2(yt[tid] - tk, __int_as_float(ye[tid]));
        s_Ek[tid] = E[k * NN + tid];
    }
    __syncthreads();

    const int evk2 = 2 * ye[k];
    float wsum = 0.0f, wnp = 0.0f;

    for (int r = 0; r < ROWS_PER_SPLIT / WAVES; ++r) {   // 10 rows per wave
        const int i = split * ROWS_PER_SPLIT + r * WAVES + wave;
        if (i == k) continue;

        const float2 pei = s_pe[i];
        const float pldi = pei.x;
        const float absi = fabsf(pldi);
        const int   sgn  = (pldi > 0.0f) ? 1 : ((pldi < 0.0f) ? -1 : 0);
        const int   cidx = 3 + sgn * (__float_as_int(pei.y) + evk2);
        const unsigned int pack = c_PACK[cidx];
        const float* __restrict__ Erow = E + i * NN;

        float acc = 0.0f;
#pragma unroll
        for (int c = 0; c < 5; ++c) {
            const int j = c * 64 + lane;
            const float2 pej = s_pe[j];
            const float pldj = pej.x;
            const int   evj  = __float_as_int(pej.y);
            int base = (-pldj > absi) ? 1 : 2;         // pldj==0 gated by ok
            base = (pldj > absi) ? 3 : base;
            const int vidx = base + evj * 3;
            int code = (int)((pack >> (2 * vidx)) & 3u);
            const bool ok = (pldj != 0.0f) && (j != i);
            code = ok ? code : 0;
            acc = fmaf((float)code, Erow[j], acc);     // 2*denom
        }
#pragma unroll
        for (int off = 32; off > 0; off >>= 1) acc += __shfl_down(acc, off);

        if (lane == 0 && acc > 0.0f) {
            // logp = L[i][k] - log(denom) = log(E[k][i]) - log(acc/2)
            wsum += logf(2.0f * s_Ek[i] / acc);
            wnp  += 1.0f;
        }
    }

    if (lane == 0) { s_sum[wave] = wsum; s_np[wave] = wnp; }
    __syncthreads();
    if (tid == 0) {
        float ts = 0.0f, tn = 0.0f;
#pragma unroll
        for (int w = 0; w < WAVES; ++w) { ts += s_sum[w]; tn += s_np[w]; }
        accv[split * NN + k]             = ts;
        accv[SPLIT * NN + split * NN + k] = tn;
    }
}

// Combine SPLIT partials per anchor, reduce 320 anchors to the scalar.
__global__ __launch_bounds__(NN) void finalize_kernel(
    const float* __restrict__ accv, float* __restrict__ out) {
    __shared__ float s_l[5];
    __shared__ float s_h[5];
    const int k = threadIdx.x;
    const int wave = k >> 6, lane = k & 63;
    float sum = 0.0f, np = 0.0f;
#pragma unroll
    for (int s = 0; s < SPLIT; ++s) {
        sum += accv[s * NN + k];
        np  += accv[SPLIT * NN + s * NN + k];
    }
    float loss = (np > 0.0f) ? (-sum / np) : 0.0f;
    float has  = (np > 0.0f) ? 1.0f : 0.0f;
#pragma unroll
    for (int off = 32; off > 0; off >>= 1) {
        loss += __shfl_down(loss, off);
        has  += __shfl_down(has, off);
    }
    if (lane == 0) { s_l[wave] = loss; s_h[wave] = has; }
    __syncthreads();
    if (k == 0) {
        float tl = 0.0f, th = 0.0f;
#pragma unroll
        for (int w = 0; w < 5; ++w) { tl += s_l[w]; th += s_h[w]; }
        out[0] = tl / th;
    }
}

extern "C" void kernel_launch(void* const* d_in, const int* in_sizes, int n_in,
                              void* d_out, int out_size, void* d_ws, size_t ws_size,
                              hipStream_t stream) {
    const float* F  = (const float*)d_in[0];   // features (320,256) f32
    const float* yt = (const float*)d_in[1];   // y_times (320,) f32
    const int*   ye = (const int*)d_in[2];     // y_events (320,) i32
    float* out = (float*)d_out;
    float* ws  = (float*)d_ws;

    float* FT   = ws;                          // 256*320
    float* E    = FT + DD * NN;                // 320*320
    float* accv = E + NN * NN;                 // 2 * SPLIT * 320

    transpose_kernel<<<dim3(5, 4), 256, 0, stream>>>(F, FT);
    pairwise_kernel<<<NN, NN, 0, stream>>>(F, FT, E);
    anchor_kernel<<<dim3(NN, SPLIT), 512, 0, stream>>>(E, yt, ye, accv);
    finalize_kernel<<<1, NN, 0, stream>>>(accv, out);
}

// Round 4
// 94.585 us; speedup vs baseline: 2.3610x; 1.0017x over previous
//
#include <hip/hip_runtime.h>
#include <math.h>

#define NN 320
#define DD 256
#define PS 328   // padded row stride for prefix arrays (need >= 321)

// Packed weight rows: code(TABLE[cidx][v]) at bit 2*v; code: mapped 1->2,
// 2->1, 0->0; weight = code*0.5. v0 is 0 in every row.
__device__ __constant__ unsigned int c_PACK[7] =
    {0x2294u, 0x1554u, 0x1254u, 0x1554u, 0x1654u, 0x1154u, 0x2294u};

// Prep: blocks 0..19 transpose F(320x256) -> FT4 (float4-packed, [d4*NN+j]);
// block 20 computes per-index sort metadata meta[j] = {t, rlt, rle, pos|ev<<16}.
__global__ __launch_bounds__(256) void prep_kernel(
    const float* __restrict__ F, const float* __restrict__ yt,
    const int* __restrict__ ye, float4* __restrict__ FT4,
    float4* __restrict__ meta) {
    __shared__ float sh[64 * 65];
    const int b = blockIdx.x;
    if (b < 20) {
        float (*tile)[65] = (float(*)[65])sh;
        const int I = b % 5;            // i-tile 0..4
        const int J = b / 5;            // d-tile 0..3 (64 dims each)
        const int lane = threadIdx.x & 63;
        const int quad = threadIdx.x >> 6;
#pragma unroll
        for (int r0 = 0; r0 < 64; r0 += 4) {
            const int r = r0 + quad;    // local i
            tile[r][lane] = F[(I * 64 + r) * DD + J * 64 + lane];
        }
        __syncthreads();
#pragma unroll
        for (int q = 0; q < 16; q += 4) {
            const int d4 = q + quad;    // local d4 (0..15)
            float4 v = make_float4(tile[lane][d4 * 4 + 0], tile[lane][d4 * 4 + 1],
                                   tile[lane][d4 * 4 + 2], tile[lane][d4 * 4 + 3]);
            FT4[(J * 16 + d4) * NN + I * 64 + lane] = v;   // coalesced in j
        }
    } else {
        float* s_t = sh;
        for (int j = threadIdx.x; j < NN; j += 256) s_t[j] = yt[j];
        __syncthreads();
        for (int j = threadIdx.x; j < NN; j += 256) {
            const float tj = s_t[j];
            int lt = 0, le = 0, pos = 0;
            for (int l = 0; l < NN; ++l) {
                const float tl = s_t[l];
                lt  += (tl < tj);
                le  += (tl <= tj);
                pos += (tl < tj) || (tl == tj && l < j);   // tie-break by index
            }
            meta[j] = make_float4(tj, __int_as_float(lt), __int_as_float(le),
                                  __int_as_float(pos | (ye[j] << 16)));
        }
    }
}

// Pair+scan: block i computes row i of L (logits) and the per-class exclusive
// prefix sums P0/P1 of E[i][.] in sorted-t order (321 entries each).
__global__ __launch_bounds__(NN) void pair_scan_kernel(
    const float* __restrict__ F, const float4* __restrict__ FT4,
    const float4* __restrict__ meta, float* __restrict__ L,
    float* __restrict__ P0, float* __restrict__ P1) {
    __shared__ __align__(16) float fi[DD];
    __shared__ float A0[2][NN];
    __shared__ float A1[2][NN];
    const int i = blockIdx.x;
    const int j = threadIdx.x;
    if (j < DD) fi[j] = F[i * DD + j];
    __syncthreads();

    const float4* __restrict__ fi4 = (const float4*)fi;
    float a0 = 0.f, a1 = 0.f, a2 = 0.f, a3 = 0.f;
#pragma unroll 8
    for (int d4 = 0; d4 < DD / 4; ++d4) {
        const float4 f4 = fi4[d4];                // ds_read_b128, broadcast
        const float4 g4 = FT4[d4 * NN + j];       // global dwordx4, coalesced
        const float u0 = f4.x - g4.x, u1 = f4.y - g4.y;
        const float u2 = f4.z - g4.z, u3 = f4.w - g4.w;
        a0 = fmaf(u0, u0, a0);
        a1 = fmaf(u1, u1, a1);
        a2 = fmaf(u2, u2, a2);
        a3 = fmaf(u3, u3, a3);
    }
    const float d2 = (a0 + a1) + (a2 + a3);
    const float nrm = (d2 > 0.f) ? sqrtf(d2) : 0.f;
    const float lg = -0.5f * nrm;                 // -norm/TEMP, TEMP=2
    L[i * NN + j] = lg;                           // symmetric: L[i][j]==L[j][i]
    const float e = expf(lg);

    // scatter into sorted-t order, split by event class
    const int pe  = __float_as_int(meta[j].w);
    const int pos = pe & 0xFFFF;
    const int ev  = pe >> 16;
    A0[0][pos] = ev ? 0.f : e;
    A1[0][pos] = ev ? e : 0.f;
    __syncthreads();

    // Hillis-Steele inclusive scan, ping-pong buffers, 9 rounds
    int src = 0;
#pragma unroll
    for (int off = 1; off < NN; off <<= 1) {
        const int dst = src ^ 1;
        float v0 = A0[src][j], v1 = A1[src][j];
        if (j >= off) { v0 += A0[src][j - off]; v1 += A1[src][j - off]; }
        A0[dst][j] = v0;
        A1[dst][j] = v1;
        __syncthreads();
        src = dst;
    }

    // exclusive prefix, plus totals at index NN
    P0[i * PS + j] = (j == 0) ? 0.f : A0[src][j - 1];
    P1[i * PS + j] = (j == 0) ? 0.f : A1[src][j - 1];
    if (j == NN - 1) {
        P0[i * PS + NN] = A0[src][j];
        P1[i * PS + NN] = A1[src][j];
    }
}

// Anchor: block k, thread i. Denominator from 6 rank-range sums; O(1) per pair.
__global__ __launch_bounds__(NN) void anchor_kernel(
    const float4* __restrict__ meta, const float* __restrict__ L,
    const float* __restrict__ P0, const float* __restrict__ P1,
    float* __restrict__ accv) {
    __shared__ float swl[5];
    __shared__ float swn[5];
    const int k = blockIdx.x;
    const int i = threadIdx.x;
    const int wave = i >> 6, lane = i & 63;

    const float4 mk = meta[k];   // uniform -> scalar loads
    const float4 mi = meta[i];   // coalesced
    const float tk = mk.x, ti = mi.x;
    const int rlt_k = __float_as_int(mk.y), rle_k = __float_as_int(mk.z);
    const int evk   = __float_as_int(mk.w) >> 16;
    const int rlt_i = __float_as_int(mi.y), rle_i = __float_as_int(mi.z);
    const int evi   = __float_as_int(mi.w) >> 16;

    const int sgn = (ti > tk) ? 1 : ((ti < tk) ? -1 : 0);
    const unsigned pack = c_PACK[3 + sgn * (evi + 2 * evk)];
    const int rlo = min(rlt_i, rlt_k);   // rank_lt(min(ti,tk))
    const int rhi = max(rle_i, rle_k);   // rank_le(max(ti,tk))

    const float* __restrict__ b0 = P0 + i * PS;
    const float* __restrict__ b1 = P1 + i * PS;
    const float q0lo = b0[rlo], q0hi = b0[rhi], q0a = b0[rlt_k], q0b = b0[rle_k], t0 = b0[NN];
    const float q1lo = b1[rlo], q1hi = b1[rhi], q1a = b1[rlt_k], q1b = b1[rle_k], t1 = b1[NN];

    const float LO0 = q0lo, HI0 = t0 - q0hi, MI0 = q0hi - q0lo - (q0b - q0a);
    const float LO1 = q1lo, HI1 = t1 - q1hi, MI1 = q1hi - q1lo - (q1b - q1a);

    const float c1 = (float)((pack >> 2) & 3u),  c2 = (float)((pack >> 4) & 3u);
    const float c3 = (float)((pack >> 6) & 3u),  c4 = (float)((pack >> 8) & 3u);
    const float c5 = (float)((pack >> 10) & 3u), c6 = (float)((pack >> 12) & 3u);

    float dx = c1 * LO0 + c2 * MI0 + c3 * HI0 + c4 * LO1 + c5 * MI1 + c6 * HI1; // 2*denom
    if (ti != tk) dx -= (float)((pack >> (2 * (2 + 3 * evi))) & 3u);  // remove j==i (E=1)

    float lp = 0.f, np = 0.f;
    if (i != k && dx > 0.f) {
        lp = L[k * NN + i] - logf(0.5f * dx);   // L[i][k]==L[k][i]
        np = 1.f;
    }
#pragma unroll
    for (int off = 32; off > 0; off >>= 1) {
        lp += __shfl_down(lp, off);
        np += __shfl_down(np, off);
    }
    if (lane == 0) { swl[wave] = lp; swn[wave] = np; }
    __syncthreads();
    if (i == 0) {
        float s = 0.f, n = 0.f;
#pragma unroll
        for (int w = 0; w < 5; ++w) { s += swl[w]; n += swn[w]; }
        accv[k] = s;
        accv[NN + k] = n;
    }
}

__global__ __launch_bounds__(NN) void finalize_kernel(
    const float* __restrict__ accv, float* __restrict__ out) {
    __shared__ float s_l[5];
    __shared__ float s_h[5];
    const int k = threadIdx.x;
    const int wave = k >> 6, lane = k & 63;
    const float np = accv[NN + k];
    float loss = (np > 0.f) ? (-accv[k] / np) : 0.f;
    float has  = (np > 0.f) ? 1.f : 0.f;
#pragma unroll
    for (int off = 32; off > 0; off >>= 1) {
        loss += __shfl_down(loss, off);
        has  += __shfl_down(has, off);
    }
    if (lane == 0) { s_l[wave] = loss; s_h[wave] = has; }
    __syncthreads();
    if (k == 0) {
        float tl = 0.f, th = 0.f;
#pragma unroll
        for (int w = 0; w < 5; ++w) { tl += s_l[w]; th += s_h[w]; }
        out[0] = tl / th;
    }
}

extern "C" void kernel_launch(void* const* d_in, const int* in_sizes, int n_in,
                              void* d_out, int out_size, void* d_ws, size_t ws_size,
                              hipStream_t stream) {
    const float* F  = (const float*)d_in[0];   // features (320,256) f32
    const float* yt = (const float*)d_in[1];   // y_times (320,) f32
    const int*   ye = (const int*)d_in[2];     // y_events (320,) i32
    float* out = (float*)d_out;
    float* ws  = (float*)d_ws;

    float4* meta = (float4*)ws;                        // 320 float4 (16B-aligned at ws base)
    float4* FT4  = (float4*)(ws + 4 * NN);             // 64*320 float4
    float*  L    = ws + 4 * NN + 4 * (DD / 4) * NN;    // 320*320
    float*  P0   = L + NN * NN;                        // 320*PS
    float*  P1   = P0 + NN * PS;                       // 320*PS
    float*  accv = P1 + NN * PS;                       // 2*320

    prep_kernel<<<21, 256, 0, stream>>>(F, yt, ye, FT4, meta);
    pair_scan_kernel<<<NN, NN, 0, stream>>>(F, FT4, meta, L, P0, P1);
    anchor_kernel<<<NN, NN, 0, stream>>>(meta, L, P0, P1, accv);
    finalize_kernel<<<1, NN, 0, stream>>>(accv, out);
}